// Round 2
// baseline (3062.561 us; speedup 1.0000x reference)
//
#include <hip/hip_runtime.h>
#include <math.h>

#define NN 100000
#define EE 640000
#define INCH 256
#define HIDC 128
#define OUTC 64

// ---------------- degree / norm ----------------
__global__ void k_deg_init(float* __restrict__ deg) {
    int i = blockIdx.x * 256 + threadIdx.x;
    if (i < NN) deg[i] = 1.0f;  // self-loop
}

__global__ void k_deg_edges(const int* __restrict__ dst, float* __restrict__ deg) {
    int e = blockIdx.x * 256 + threadIdx.x;
    if (e < EE) atomicAdd(&deg[dst[e]], 1.0f);
}

__global__ void k_rsqrt(float* __restrict__ deg) {
    int i = blockIdx.x * 256 + threadIdx.x;
    if (i < NN) deg[i] = rsqrtf(deg[i]);
}

__device__ __forceinline__ void fma4(float4& a, float s, const float4& v) {
    a.x = fmaf(s, v.x, a.x);
    a.y = fmaf(s, v.y, a.y);
    a.z = fmaf(s, v.z, a.z);
    a.w = fmaf(s, v.w, a.w);
}

// ---------------- GEMM1: XW1 = x @ W1  [N,256]x[256,128] ----------------
__global__ __launch_bounds__(256) void k_gemm1(const float* __restrict__ x,
                                               const float* __restrict__ W,
                                               float* __restrict__ out) {
    int tid = threadIdx.x;
    int cg = tid & 31;       // column group: 4 consecutive cols
    int rl = tid >> 5;       // 0..7 local row
    int row = blockIdx.x * 8 + rl;
    if (row >= NN) return;
    const float* xr = x + (size_t)row * INCH;
    const float* wp = W + cg * 4;
    float4 acc = make_float4(0.f, 0.f, 0.f, 0.f);
#pragma unroll 4
    for (int k = 0; k < INCH; k += 4) {
        float4 xv = *(const float4*)(xr + k);
        float4 w0 = *(const float4*)(wp + (size_t)(k + 0) * HIDC);
        float4 w1 = *(const float4*)(wp + (size_t)(k + 1) * HIDC);
        float4 w2 = *(const float4*)(wp + (size_t)(k + 2) * HIDC);
        float4 w3 = *(const float4*)(wp + (size_t)(k + 3) * HIDC);
        fma4(acc, xv.x, w0);
        fma4(acc, xv.y, w1);
        fma4(acc, xv.z, w2);
        fma4(acc, xv.w, w3);
    }
    *(float4*)(out + (size_t)row * HIDC + cg * 4) = acc;
}

// ---------------- self-loop init: dst[i][:] = src[i][:] * dinv[i]^2 ----------------
__global__ __launch_bounds__(256) void k_selfloop(const float* __restrict__ srcb,
                                                  const float* __restrict__ dinv,
                                                  float* __restrict__ dstb) {
    int idx = blockIdx.x * 256 + threadIdx.x;  // over NN*32 float4s
    if (idx >= NN * 32) return;
    int i = idx >> 5;
    float d = dinv[i];
    float n = d * d;
    float4 v = ((const float4*)srcb)[idx];
    v.x *= n; v.y *= n; v.z *= n; v.w *= n;
    ((float4*)dstb)[idx] = v;
}

// ---------------- scatter: out[dst] += feat[src] * dinv[src]*dinv[dst] ----------------
__global__ __launch_bounds__(256) void k_scatter(const float* __restrict__ feat,
                                                 const int* __restrict__ srcp,
                                                 const int* __restrict__ dstp,
                                                 const float* __restrict__ dinv,
                                                 float* __restrict__ out) {
    int tid = threadIdx.x;
    int q = tid & 31;        // 32 threads per edge, 4 channels each
    int el = tid >> 5;       // 0..7
    int e = blockIdx.x * 8 + el;
    if (e >= EE) return;
    int s = srcp[e];
    int d = dstp[e];
    float norm = dinv[s] * dinv[d];
    float4 v = *(const float4*)(feat + (size_t)s * HIDC + q * 4);
    float* o = out + (size_t)d * HIDC + q * 4;
    atomicAdd(o + 0, v.x * norm);
    atomicAdd(o + 1, v.y * norm);
    atomicAdd(o + 2, v.z * norm);
    atomicAdd(o + 3, v.w * norm);
}

// ---------------- h = relu(agg + b1) ----------------
__global__ __launch_bounds__(256) void k_relu_bias(const float* __restrict__ agg,
                                                   const float* __restrict__ b1,
                                                   float* __restrict__ h) {
    int idx = blockIdx.x * 256 + threadIdx.x;  // over NN*32 float4s
    if (idx >= NN * 32) return;
    int c4 = (idx & 31) * 4;
    float4 v = ((const float4*)agg)[idx];
    float4 b = *(const float4*)(b1 + c4);
    v.x = fmaxf(v.x + b.x, 0.f);
    v.y = fmaxf(v.y + b.y, 0.f);
    v.z = fmaxf(v.z + b.z, 0.f);
    v.w = fmaxf(v.w + b.w, 0.f);
    ((float4*)h)[idx] = v;
}

// ---------------- GEMM2: [mu|logstd] = agg2 @ [W_mu|W_ls] + [b_mu|b_ls] ----------------
__global__ __launch_bounds__(256) void k_gemm2(const float* __restrict__ agg,
                                               const float* __restrict__ Wmu,
                                               const float* __restrict__ bmu,
                                               const float* __restrict__ Wls,
                                               const float* __restrict__ bls,
                                               float* __restrict__ out) {
    int tid = threadIdx.x;
    int cg = tid & 31;       // 0..15 -> mu cols, 16..31 -> logstd cols
    int rl = tid >> 5;
    int row = blockIdx.x * 8 + rl;
    if (row >= NN) return;
    const float* ar = agg + (size_t)row * HIDC;
    bool ismu = cg < 16;
    int cc = (ismu ? cg : cg - 16) * 4;
    const float* W = (ismu ? Wmu : Wls) + cc;
    float4 acc = make_float4(0.f, 0.f, 0.f, 0.f);
#pragma unroll 4
    for (int k = 0; k < HIDC; k += 4) {
        float4 av = *(const float4*)(ar + k);
        float4 w0 = *(const float4*)(W + (size_t)(k + 0) * OUTC);
        float4 w1 = *(const float4*)(W + (size_t)(k + 1) * OUTC);
        float4 w2 = *(const float4*)(W + (size_t)(k + 2) * OUTC);
        float4 w3 = *(const float4*)(W + (size_t)(k + 3) * OUTC);
        fma4(acc, av.x, w0);
        fma4(acc, av.y, w1);
        fma4(acc, av.z, w2);
        fma4(acc, av.w, w3);
    }
    const float* bb = (ismu ? bmu : bls) + cc;
    acc.x += bb[0]; acc.y += bb[1]; acc.z += bb[2]; acc.w += bb[3];
    float* op = out + (ismu ? (size_t)0 : (size_t)NN * OUTC) + (size_t)row * OUTC + cc;
    *(float4*)op = acc;
}

extern "C" void kernel_launch(void* const* d_in, const int* in_sizes, int n_in,
                              void* d_out, int out_size, void* d_ws, size_t ws_size,
                              hipStream_t stream) {
    const float* x   = (const float*)d_in[0];
    const float* W1  = (const float*)d_in[1];
    const float* b1  = (const float*)d_in[2];
    const float* Wmu = (const float*)d_in[3];
    const float* bmu = (const float*)d_in[4];
    const float* Wls = (const float*)d_in[5];
    const float* bls = (const float*)d_in[6];
    const int*   ei  = (const int*)d_in[7];
    const int* srcp = ei;        // edge_index[0]
    const int* dstp = ei + EE;   // edge_index[1]

    float* out  = (float*)d_out;
    float* dinv = (float*)d_ws;          // N floats (deg, then rsqrt in place)
    float* bufB = dinv + NN;             // N*128 floats (aggregation buffer)
    float* bufA = out;                   // N*128 floats: XW1, then h (out_size == N*128)

    const int nb_n   = (NN + 255) / 256;
    const int nb_e   = (EE + 255) / 256;
    const int nb_f4  = (NN * 32 + 255) / 256;
    const int nb_row = (NN + 7) / 8;
    const int nb_sc  = (EE + 7) / 8;

    // degree + norm
    k_deg_init<<<nb_n, 256, 0, stream>>>(dinv);
    k_deg_edges<<<nb_e, 256, 0, stream>>>(dstp, dinv);
    k_rsqrt<<<nb_n, 256, 0, stream>>>(dinv);

    // layer 1: XW1, aggregate, relu+bias
    k_gemm1<<<nb_row, 256, 0, stream>>>(x, W1, bufA);
    k_selfloop<<<nb_f4, 256, 0, stream>>>(bufA, dinv, bufB);
    k_scatter<<<nb_sc, 256, 0, stream>>>(bufA, srcp, dstp, dinv, bufB);
    k_relu_bias<<<nb_f4, 256, 0, stream>>>(bufB, b1, bufA);  // h -> bufA (d_out)

    // layer 2/3: aggregate h once, then fused GEMM into mu|logstd
    k_selfloop<<<nb_f4, 256, 0, stream>>>(bufA, dinv, bufB);
    k_scatter<<<nb_sc, 256, 0, stream>>>(bufA, srcp, dstp, dinv, bufB);
    k_gemm2<<<nb_row, 256, 0, stream>>>(bufB, Wmu, bmu, Wls, bls, out);
}

// Round 3
// 671.869 us; speedup vs baseline: 4.5583x; 4.5583x over previous
//
#include <hip/hip_runtime.h>
#include <math.h>

#define NN 100000
#define EE 640000
#define INCH 256
#define HIDC 128
#define OUTC 64
#define NCHUNK ((NN + 255) / 256)   // 391 scan chunks

// ---------------- degree ----------------
__global__ void k_deg_zero(int* __restrict__ deg) {
    int i = blockIdx.x * 256 + threadIdx.x;
    if (i < NN) deg[i] = 0;
}

__global__ void k_deg_count(const int* __restrict__ dstp, int* __restrict__ deg) {
    int e = blockIdx.x * 256 + threadIdx.x;
    if (e < EE) atomicAdd(&deg[dstp[e]], 1);
}

// ---------------- scan (exclusive prefix over deg) ----------------
__global__ __launch_bounds__(256) void k_scan1(const int* __restrict__ deg,
                                               int* __restrict__ partials) {
    int i = blockIdx.x * 256 + threadIdx.x;
    int v = (i < NN) ? deg[i] : 0;
    for (int o = 32; o; o >>= 1) v += __shfl_down(v, o, 64);
    __shared__ int sm[4];
    if ((threadIdx.x & 63) == 0) sm[threadIdx.x >> 6] = v;
    __syncthreads();
    if (threadIdx.x == 0) partials[blockIdx.x] = sm[0] + sm[1] + sm[2] + sm[3];
}

__global__ __launch_bounds__(512) void k_scan2(int* __restrict__ partials) {
    __shared__ int sm[512];
    int t = threadIdx.x;
    int v = (t < NCHUNK) ? partials[t] : 0;
    sm[t] = v;
    __syncthreads();
    for (int o = 1; o < 512; o <<= 1) {
        int add = (t >= o) ? sm[t - o] : 0;
        __syncthreads();
        sm[t] += add;
        __syncthreads();
    }
    if (t < NCHUNK) partials[t] = sm[t] - v;  // exclusive
}

__global__ __launch_bounds__(256) void k_scan3(const int* __restrict__ deg,
                                               const int* __restrict__ partials,
                                               int* __restrict__ row_off,
                                               int* __restrict__ cursor,
                                               float* __restrict__ dinv) {
    int t = threadIdx.x;
    int i = blockIdx.x * 256 + t;
    int v = (i < NN) ? deg[i] : 0;
    __shared__ int sm[256];
    sm[t] = v;
    __syncthreads();
    for (int o = 1; o < 256; o <<= 1) {
        int add = (t >= o) ? sm[t - o] : 0;
        __syncthreads();
        sm[t] += add;
        __syncthreads();
    }
    if (i < NN) {
        int excl = partials[blockIdx.x] + sm[t] - v;
        row_off[i] = excl;
        cursor[i] = excl;
        dinv[i] = rsqrtf((float)(v + 1));  // +1 self-loop
    }
}

// ---------------- CSR fill (order within bucket irrelevant) ----------------
__global__ void k_fill(const int* __restrict__ srcp, const int* __restrict__ dstp,
                       int* __restrict__ cursor, int* __restrict__ esrc) {
    int e = blockIdx.x * 256 + threadIdx.x;
    if (e < EE) {
        int d = dstp[e];
        int pos = atomicAdd(&cursor[d], 1);
        esrc[pos] = srcp[e];
    }
}

__device__ __forceinline__ void fma4(float4& a, float s, const float4& v) {
    a.x = fmaf(s, v.x, a.x);
    a.y = fmaf(s, v.y, a.y);
    a.z = fmaf(s, v.z, a.z);
    a.w = fmaf(s, v.w, a.w);
}

// ---------------- GEMM1: XW1 = x @ W1  [N,256]x[256,128], 4 rows/thread ----------------
__global__ __launch_bounds__(256) void k_gemm1(const float* __restrict__ x,
                                               const float* __restrict__ W,
                                               float* __restrict__ out) {
    int tid = threadIdx.x;
    int cg = tid & 31;   // 4 consecutive cols
    int rl = tid >> 5;   // 0..7
    int row0 = blockIdx.x * 32 + rl;  // rows row0, +8, +16, +24 (grid exact: 3125*32=100000)
    const float* xr = x + (size_t)row0 * INCH;
    const float* wp = W + cg * 4;
    float4 a0 = make_float4(0.f, 0.f, 0.f, 0.f);
    float4 a1 = a0, a2 = a0, a3 = a0;
#pragma unroll 2
    for (int k = 0; k < INCH; k += 4) {
        float4 w0 = *(const float4*)(wp + (size_t)(k + 0) * HIDC);
        float4 w1 = *(const float4*)(wp + (size_t)(k + 1) * HIDC);
        float4 w2 = *(const float4*)(wp + (size_t)(k + 2) * HIDC);
        float4 w3 = *(const float4*)(wp + (size_t)(k + 3) * HIDC);
        float4 x0 = *(const float4*)(xr + k);
        float4 x1 = *(const float4*)(xr + 8 * INCH + k);
        float4 x2 = *(const float4*)(xr + 16 * INCH + k);
        float4 x3 = *(const float4*)(xr + 24 * INCH + k);
        fma4(a0, x0.x, w0); fma4(a0, x0.y, w1); fma4(a0, x0.z, w2); fma4(a0, x0.w, w3);
        fma4(a1, x1.x, w0); fma4(a1, x1.y, w1); fma4(a1, x1.z, w2); fma4(a1, x1.w, w3);
        fma4(a2, x2.x, w0); fma4(a2, x2.y, w1); fma4(a2, x2.z, w2); fma4(a2, x2.w, w3);
        fma4(a3, x3.x, w0); fma4(a3, x3.y, w1); fma4(a3, x3.z, w2); fma4(a3, x3.w, w3);
    }
    float* op = out + (size_t)row0 * HIDC + cg * 4;
    *(float4*)(op + 0 * 8 * HIDC) = a0;
    *(float4*)(op + 1 * 8 * HIDC) = a1;
    *(float4*)(op + 2 * 8 * HIDC) = a2;
    *(float4*)(op + 3 * 8 * HIDC) = a3;
}

// ---------------- gather aggregation: one wave per dst row ----------------
template <bool RELU>
__global__ __launch_bounds__(256) void k_gather(const float* __restrict__ feat,
                                                const int* __restrict__ esrc,
                                                const int* __restrict__ row_off,
                                                const int* __restrict__ deg,
                                                const float* __restrict__ dinv,
                                                const float* __restrict__ bias,
                                                float* __restrict__ out) {
    int gid = blockIdx.x * 256 + threadIdx.x;
    int d = gid >> 6;          // one wave per dst node
    int lane = threadIdx.x & 63;
    if (d >= NN) return;
    const float2* fp = (const float2*)feat;
    float dd = dinv[d];
    float2 self = fp[(size_t)d * 64 + lane];
    float sw = dd * dd;
    float2 acc;
    acc.x = self.x * sw;
    acc.y = self.y * sw;
    int off = row_off[d];
    int cnt = deg[d];
    for (int base = 0; base < cnt; base += 64) {
        int m = min(64, cnt - base);
        int sj = (lane < m) ? esrc[off + base + lane] : 0;
        float dj = (lane < m) ? dinv[sj] : 0.f;
        for (int j = 0; j < m; j++) {
            int s = __shfl(sj, j, 64);
            float nw = __shfl(dj, j, 64) * dd;
            float2 v = fp[(size_t)s * 64 + lane];
            acc.x = fmaf(v.x, nw, acc.x);
            acc.y = fmaf(v.y, nw, acc.y);
        }
    }
    if (RELU) {
        float2 b = ((const float2*)bias)[lane];
        acc.x = fmaxf(acc.x + b.x, 0.f);
        acc.y = fmaxf(acc.y + b.y, 0.f);
    }
    ((float2*)out)[(size_t)d * 64 + lane] = acc;
}

// ---------------- GEMM2: [mu|logstd] = agg2 @ [W_mu|W_ls] + bias, 4 rows/thread ----------------
__global__ __launch_bounds__(256) void k_gemm2(const float* __restrict__ agg,
                                               const float* __restrict__ Wmu,
                                               const float* __restrict__ bmu,
                                               const float* __restrict__ Wls,
                                               const float* __restrict__ bls,
                                               float* __restrict__ out) {
    int tid = threadIdx.x;
    int cg = tid & 31;   // 0..15 -> mu, 16..31 -> logstd
    int rl = tid >> 5;
    int row0 = blockIdx.x * 32 + rl;
    bool ismu = cg < 16;
    int cc = (ismu ? cg : cg - 16) * 4;
    const float* W = (ismu ? Wmu : Wls) + cc;
    const float* ar = agg + (size_t)row0 * HIDC;
    float4 a0 = make_float4(0.f, 0.f, 0.f, 0.f);
    float4 a1 = a0, a2 = a0, a3 = a0;
#pragma unroll 2
    for (int k = 0; k < HIDC; k += 4) {
        float4 w0 = *(const float4*)(W + (size_t)(k + 0) * OUTC);
        float4 w1 = *(const float4*)(W + (size_t)(k + 1) * OUTC);
        float4 w2 = *(const float4*)(W + (size_t)(k + 2) * OUTC);
        float4 w3 = *(const float4*)(W + (size_t)(k + 3) * OUTC);
        float4 x0 = *(const float4*)(ar + k);
        float4 x1 = *(const float4*)(ar + 8 * HIDC + k);
        float4 x2 = *(const float4*)(ar + 16 * HIDC + k);
        float4 x3 = *(const float4*)(ar + 24 * HIDC + k);
        fma4(a0, x0.x, w0); fma4(a0, x0.y, w1); fma4(a0, x0.z, w2); fma4(a0, x0.w, w3);
        fma4(a1, x1.x, w0); fma4(a1, x1.y, w1); fma4(a1, x1.z, w2); fma4(a1, x1.w, w3);
        fma4(a2, x2.x, w0); fma4(a2, x2.y, w1); fma4(a2, x2.z, w2); fma4(a2, x2.w, w3);
        fma4(a3, x3.x, w0); fma4(a3, x3.y, w1); fma4(a3, x3.z, w2); fma4(a3, x3.w, w3);
    }
    const float* bb = (ismu ? bmu : bls) + cc;
    float4 bv = *(const float4*)bb;
    a0.x += bv.x; a0.y += bv.y; a0.z += bv.z; a0.w += bv.w;
    a1.x += bv.x; a1.y += bv.y; a1.z += bv.z; a1.w += bv.w;
    a2.x += bv.x; a2.y += bv.y; a2.z += bv.z; a2.w += bv.w;
    a3.x += bv.x; a3.y += bv.y; a3.z += bv.z; a3.w += bv.w;
    float* op = out + (ismu ? (size_t)0 : (size_t)NN * OUTC) + (size_t)row0 * OUTC + cc;
    *(float4*)(op + 0 * 8 * OUTC) = a0;
    *(float4*)(op + 1 * 8 * OUTC) = a1;
    *(float4*)(op + 2 * 8 * OUTC) = a2;
    *(float4*)(op + 3 * 8 * OUTC) = a3;
}

extern "C" void kernel_launch(void* const* d_in, const int* in_sizes, int n_in,
                              void* d_out, int out_size, void* d_ws, size_t ws_size,
                              hipStream_t stream) {
    const float* x   = (const float*)d_in[0];
    const float* W1  = (const float*)d_in[1];
    const float* b1  = (const float*)d_in[2];
    const float* Wmu = (const float*)d_in[3];
    const float* bmu = (const float*)d_in[4];
    const float* Wls = (const float*)d_in[5];
    const float* bls = (const float*)d_in[6];
    const int*   ei  = (const int*)d_in[7];
    const int* srcp = ei;        // edge_index[0]
    const int* dstp = ei + EE;   // edge_index[1]

    float* out = (float*)d_out;

    // workspace layout
    char* wsb = (char*)d_ws;
    float* bufB    = (float*)wsb;                       // N*128 floats (51.2 MB)
    int*   deg     = (int*)(wsb + (size_t)NN * HIDC * 4);
    int*   row_off = deg + NN;
    int*   cursor  = row_off + NN;
    float* dinv    = (float*)(cursor + NN);
    int*   esrc    = (int*)(dinv + NN);                 // E ints
    int*   partials = esrc + EE;                        // NCHUNK ints

    const int nb_n = (NN + 255) / 256;
    const int nb_e = (EE + 255) / 256;
    const int nb_g = (NN * 64 + 255) / 256;   // gather: one wave per node
    const int nb_r = NN / 32;                  // 3125 (exact)

    // CSR build + norm
    k_deg_zero<<<nb_n, 256, 0, stream>>>(deg);
    k_deg_count<<<nb_e, 256, 0, stream>>>(dstp, deg);
    k_scan1<<<NCHUNK, 256, 0, stream>>>(deg, partials);
    k_scan2<<<1, 512, 0, stream>>>(partials);
    k_scan3<<<NCHUNK, 256, 0, stream>>>(deg, partials, row_off, cursor, dinv);
    k_fill<<<nb_e, 256, 0, stream>>>(srcp, dstp, cursor, esrc);

    // layer 1: XW1 -> bufB; h = relu(agg(bufB) + b1) -> d_out
    k_gemm1<<<nb_r, 256, 0, stream>>>(x, W1, bufB);
    k_gather<true><<<nb_g, 256, 0, stream>>>(bufB, esrc, row_off, deg, dinv, b1, out);

    // layer 2/3: agg2 = agg(h) -> bufB; [mu|logstd] = bufB @ [Wmu|Wls] + b -> d_out
    k_gather<false><<<nb_g, 256, 0, stream>>>(out, esrc, row_off, deg, dinv, nullptr, bufB);
    k_gemm2<<<nb_r, 256, 0, stream>>>(bufB, Wmu, bmu, Wls, bls, out);
}

// Round 4
// 463.529 us; speedup vs baseline: 6.6071x; 1.4495x over previous
//
#include <hip/hip_runtime.h>
#include <math.h>

#define NN 100000
#define EE 640000
#define INCH 256
#define HIDC 128
#define OUTC 64
#define NCHUNK ((NN + 255) / 256)   // 391 scan chunks

typedef __attribute__((ext_vector_type(8))) short short8;
typedef __attribute__((ext_vector_type(4))) float floatx4;

__device__ __forceinline__ short f2bf(float f) {
    unsigned u = __float_as_uint(f);
    u += 0x7fff + ((u >> 16) & 1);   // round-to-nearest-even
    return (short)(u >> 16);
}

// ---------------- degree ----------------
__global__ void k_deg_zero(int* __restrict__ deg) {
    int i = blockIdx.x * 256 + threadIdx.x;
    if (i < NN) deg[i] = 0;
}

__global__ void k_deg_count(const int* __restrict__ dstp, int* __restrict__ deg) {
    int e = blockIdx.x * 256 + threadIdx.x;
    if (e < EE) atomicAdd(&deg[dstp[e]], 1);
}

// ---------------- scan (exclusive prefix over deg) ----------------
__global__ __launch_bounds__(256) void k_scan1(const int* __restrict__ deg,
                                               int* __restrict__ partials) {
    int i = blockIdx.x * 256 + threadIdx.x;
    int v = (i < NN) ? deg[i] : 0;
    for (int o = 32; o; o >>= 1) v += __shfl_down(v, o, 64);
    __shared__ int sm[4];
    if ((threadIdx.x & 63) == 0) sm[threadIdx.x >> 6] = v;
    __syncthreads();
    if (threadIdx.x == 0) partials[blockIdx.x] = sm[0] + sm[1] + sm[2] + sm[3];
}

__global__ __launch_bounds__(512) void k_scan2(int* __restrict__ partials) {
    __shared__ int sm[512];
    int t = threadIdx.x;
    int v = (t < NCHUNK) ? partials[t] : 0;
    sm[t] = v;
    __syncthreads();
    for (int o = 1; o < 512; o <<= 1) {
        int add = (t >= o) ? sm[t - o] : 0;
        __syncthreads();
        sm[t] += add;
        __syncthreads();
    }
    if (t < NCHUNK) partials[t] = sm[t] - v;  // exclusive
}

__global__ __launch_bounds__(256) void k_scan3(const int* __restrict__ deg,
                                               const int* __restrict__ partials,
                                               int* __restrict__ row_off,
                                               int* __restrict__ cursor,
                                               float* __restrict__ dinv) {
    int t = threadIdx.x;
    int i = blockIdx.x * 256 + t;
    int v = (i < NN) ? deg[i] : 0;
    __shared__ int sm[256];
    sm[t] = v;
    __syncthreads();
    for (int o = 1; o < 256; o <<= 1) {
        int add = (t >= o) ? sm[t - o] : 0;
        __syncthreads();
        sm[t] += add;
        __syncthreads();
    }
    if (i < NN) {
        int excl = partials[blockIdx.x] + sm[t] - v;
        row_off[i] = excl;
        cursor[i] = excl;
        dinv[i] = rsqrtf((float)(v + 1));  // +1 self-loop
    }
}

// ---------------- CSR fill ----------------
__global__ void k_fill(const int* __restrict__ srcp, const int* __restrict__ dstp,
                       int* __restrict__ cursor, int* __restrict__ esrc) {
    int e = blockIdx.x * 256 + threadIdx.x;
    if (e < EE) {
        int d = dstp[e];
        int pos = atomicAdd(&cursor[d], 1);
        esrc[pos] = srcp[e];
    }
}

// ---------------- weight prep: transpose + bf16 ----------------
// wt  [128][256] = bf16(W1[k][n])         (64 KB)
// wct [128][128] = bf16([Wmu|Wls][k][n])  (32 KB)
// bcat[128]      = [bmu|bls]
__global__ void k_prep(const float* __restrict__ W1,
                       const float* __restrict__ Wmu, const float* __restrict__ bmu,
                       const float* __restrict__ Wls, const float* __restrict__ bls,
                       short* __restrict__ wt, short* __restrict__ wct,
                       float* __restrict__ bcat) {
    int i = blockIdx.x * 256 + threadIdx.x;
    if (i < 32768) {
        int n = i >> 8, k = i & 255;
        wt[i] = f2bf(W1[k * HIDC + n]);
    } else if (i < 32768 + 16384) {
        int j = i - 32768;
        int n = j >> 7, k = j & 127;
        float v = (n < OUTC) ? Wmu[k * OUTC + n] : Wls[k * OUTC + (n - OUTC)];
        wct[j] = f2bf(v);
    } else if (i < 32768 + 16384 + 128) {
        int c = i - (32768 + 16384);
        bcat[c] = (c < OUTC) ? bmu[c] : bls[c - OUTC];
    }
}

// ---------------- MFMA GEMM1: out[M,128] = bf16(x[M,256]) @ wt^T ----------------
__global__ __launch_bounds__(256) void k_mgemm1(const float* __restrict__ x,
                                                const short* __restrict__ wt,
                                                float* __restrict__ out) {
    int wave = threadIdx.x >> 6;
    int lane = threadIdx.x & 63;
    int m = lane & 15, quad = lane >> 4;
    int arow = blockIdx.x * 64 + wave * 16 + m;
    int arowc = min(arow, NN - 1);
    const float* xr = x + (size_t)arowc * INCH + quad * 8;
    floatx4 acc[8];
#pragma unroll
    for (int i = 0; i < 8; i++) acc[i] = (floatx4)(0.f);
#pragma unroll
    for (int k0 = 0; k0 < INCH; k0 += 32) {
        float4 f0 = *(const float4*)(xr + k0);
        float4 f1 = *(const float4*)(xr + k0 + 4);
        short8 a;
        a[0] = f2bf(f0.x); a[1] = f2bf(f0.y); a[2] = f2bf(f0.z); a[3] = f2bf(f0.w);
        a[4] = f2bf(f1.x); a[5] = f2bf(f1.y); a[6] = f2bf(f1.z); a[7] = f2bf(f1.w);
        const short* wq = wt + k0 + quad * 8 + (size_t)m * INCH;
#pragma unroll
        for (int nt = 0; nt < 8; nt++) {
            short8 b = *(const short8*)(wq + (size_t)nt * 16 * INCH);
            acc[nt] = __builtin_amdgcn_mfma_f32_16x16x32_bf16(a, b, acc[nt], 0, 0, 0);
        }
    }
    int col = lane & 15;
    int rbase = blockIdx.x * 64 + wave * 16 + quad * 4;
#pragma unroll
    for (int nt = 0; nt < 8; nt++) {
#pragma unroll
        for (int r = 0; r < 4; r++) {
            int rr = rbase + r;
            if (rr < NN) out[(size_t)rr * HIDC + nt * 16 + col] = acc[nt][r];
        }
    }
}

// ---------------- MFMA GEMM2: [mu|logstd] = bf16(agg[M,128]) @ wct^T + bcat ----------------
__global__ __launch_bounds__(256) void k_mgemm2(const float* __restrict__ agg,
                                                const short* __restrict__ wct,
                                                const float* __restrict__ bcat,
                                                float* __restrict__ out) {
    int wave = threadIdx.x >> 6;
    int lane = threadIdx.x & 63;
    int m = lane & 15, quad = lane >> 4;
    int arow = blockIdx.x * 64 + wave * 16 + m;
    int arowc = min(arow, NN - 1);
    const float* ar = agg + (size_t)arowc * HIDC + quad * 8;
    floatx4 acc[8];
#pragma unroll
    for (int i = 0; i < 8; i++) acc[i] = (floatx4)(0.f);
#pragma unroll
    for (int k0 = 0; k0 < HIDC; k0 += 32) {
        float4 f0 = *(const float4*)(ar + k0);
        float4 f1 = *(const float4*)(ar + k0 + 4);
        short8 a;
        a[0] = f2bf(f0.x); a[1] = f2bf(f0.y); a[2] = f2bf(f0.z); a[3] = f2bf(f0.w);
        a[4] = f2bf(f1.x); a[5] = f2bf(f1.y); a[6] = f2bf(f1.z); a[7] = f2bf(f1.w);
        const short* wq = wct + k0 + quad * 8 + (size_t)m * HIDC;
#pragma unroll
        for (int nt = 0; nt < 8; nt++) {
            short8 b = *(const short8*)(wq + (size_t)nt * 16 * HIDC);
            acc[nt] = __builtin_amdgcn_mfma_f32_16x16x32_bf16(a, b, acc[nt], 0, 0, 0);
        }
    }
    int col = lane & 15;
    int rbase = blockIdx.x * 64 + wave * 16 + quad * 4;
#pragma unroll
    for (int nt = 0; nt < 8; nt++) {
        int c = nt * 16 + col;
        float bv = bcat[c];
        float* obase = (c < OUTC) ? (out + c) : (out + (size_t)NN * OUTC + (c - OUTC));
#pragma unroll
        for (int r = 0; r < 4; r++) {
            int rr = rbase + r;
            if (rr < NN) obase[(size_t)rr * OUTC] = acc[nt][r] + bv;
        }
    }
}

__device__ __forceinline__ void fma4(float4& a, float s, const float4& v) {
    a.x = fmaf(s, v.x, a.x);
    a.y = fmaf(s, v.y, a.y);
    a.z = fmaf(s, v.z, a.z);
    a.w = fmaf(s, v.w, a.w);
}

// ---------------- gather aggregation: one 32-lane half-wave per dst row ----------------
template <bool RELU>
__global__ __launch_bounds__(256) void k_gather(const float* __restrict__ feat,
                                                const int* __restrict__ esrc,
                                                const int* __restrict__ row_off,
                                                const int* __restrict__ deg,
                                                const float* __restrict__ dinv,
                                                const float* __restrict__ bias,
                                                float* __restrict__ out) {
    int gid = blockIdx.x * 256 + threadIdx.x;
    int d = gid >> 5;          // one 32-lane group per dst node
    int l = threadIdx.x & 31;  // 32 lanes x float4 = 128 ch
    if (d >= NN) return;
    const float4* fp = (const float4*)feat;
    float dd = dinv[d];
    float4 self = fp[(size_t)d * 32 + l];
    float sw = dd * dd;
    float4 acc;
    acc.x = self.x * sw; acc.y = self.y * sw;
    acc.z = self.z * sw; acc.w = self.w * sw;
    int off = row_off[d];
    int cnt = deg[d];
    for (int base = 0; base < cnt; base += 32) {
        int mm = min(32, cnt - base);
        int sj = (l < mm) ? esrc[off + base + l] : 0;
        float dj = (l < mm) ? dinv[sj] : 0.f;
        for (int j = 0; j < mm; j++) {
            int s = __shfl(sj, j, 32);
            float nw = __shfl(dj, j, 32) * dd;
            float4 v = fp[(size_t)s * 32 + l];
            fma4(acc, nw, v);
        }
    }
    if (RELU) {
        float4 b = ((const float4*)bias)[l];
        acc.x = fmaxf(acc.x + b.x, 0.f);
        acc.y = fmaxf(acc.y + b.y, 0.f);
        acc.z = fmaxf(acc.z + b.z, 0.f);
        acc.w = fmaxf(acc.w + b.w, 0.f);
    }
    ((float4*)out)[(size_t)d * 32 + l] = acc;
}

extern "C" void kernel_launch(void* const* d_in, const int* in_sizes, int n_in,
                              void* d_out, int out_size, void* d_ws, size_t ws_size,
                              hipStream_t stream) {
    const float* x   = (const float*)d_in[0];
    const float* W1  = (const float*)d_in[1];
    const float* b1  = (const float*)d_in[2];
    const float* Wmu = (const float*)d_in[3];
    const float* bmu = (const float*)d_in[4];
    const float* Wls = (const float*)d_in[5];
    const float* bls = (const float*)d_in[6];
    const int*   ei  = (const int*)d_in[7];
    const int* srcp = ei;        // edge_index[0]
    const int* dstp = ei + EE;   // edge_index[1]

    float* out = (float*)d_out;

    // workspace layout
    char* wsb = (char*)d_ws;
    float* bufB    = (float*)wsb;                       // N*128 floats (51.2 MB)
    int*   deg     = (int*)(wsb + (size_t)NN * HIDC * 4);
    int*   row_off = deg + NN;
    int*   cursor  = row_off + NN;
    float* dinv    = (float*)(cursor + NN);
    int*   esrc    = (int*)(dinv + NN);                 // E ints
    int*   partials = esrc + EE;                        // NCHUNK ints
    short* wt      = (short*)(partials + NCHUNK + 1);   // 128*256 bf16
    short* wct     = wt + 128 * 256;                    // 128*128 bf16
    float* bcat    = (float*)(wct + 128 * 128);         // 128 f32

    const int nb_n = (NN + 255) / 256;
    const int nb_e = (EE + 255) / 256;
    const int nb_g = (NN * 32) / 256;          // 12500 exact
    const int nb_m = (NN + 63) / 64;           // 1563 MFMA blocks

    // CSR build + norm + weight prep
    k_deg_zero<<<nb_n, 256, 0, stream>>>(deg);
    k_deg_count<<<nb_e, 256, 0, stream>>>(dstp, deg);
    k_scan1<<<NCHUNK, 256, 0, stream>>>(deg, partials);
    k_scan2<<<1, 512, 0, stream>>>(partials);
    k_scan3<<<NCHUNK, 256, 0, stream>>>(deg, partials, row_off, cursor, dinv);
    k_fill<<<nb_e, 256, 0, stream>>>(srcp, dstp, cursor, esrc);
    k_prep<<<193, 256, 0, stream>>>(W1, Wmu, bmu, Wls, bls, wt, wct, bcat);

    // layer 1: XW1 -> bufB (MFMA); h = relu(agg(bufB) + b1) -> d_out
    k_mgemm1<<<nb_m, 256, 0, stream>>>(x, wt, bufB);
    k_gather<true><<<nb_g, 256, 0, stream>>>(bufB, esrc, row_off, deg, dinv, b1, out);

    // layer 2/3: agg2 = agg(h) -> bufB; [mu|logstd] = bufB @ [Wmu|Wls] + b -> d_out (MFMA)
    k_gather<false><<<nb_g, 256, 0, stream>>>(out, esrc, row_off, deg, dinv, nullptr, bufB);
    k_mgemm2<<<nb_m, 256, 0, stream>>>(bufB, wct, bcat, out);
}

// Round 5
// 383.221 us; speedup vs baseline: 7.9916x; 1.2096x over previous
//
#include <hip/hip_runtime.h>
#include <math.h>

#define NN 100000
#define EE 640000
#define INCH 256
#define HIDC 128
#define OUTC 64
#define NCHUNK ((NN + 255) / 256)   // 391 scan chunks

typedef __attribute__((ext_vector_type(8))) short short8;
typedef __attribute__((ext_vector_type(8))) unsigned short ushort8;
typedef __attribute__((ext_vector_type(4))) float floatx4;

__device__ __forceinline__ short f2bf(float f) {
    unsigned u = __float_as_uint(f);
    u += 0x7fff + ((u >> 16) & 1);   // round-to-nearest-even
    return (short)(u >> 16);
}

__device__ __forceinline__ float bf2f(unsigned short u) {
    return __uint_as_float(((unsigned)u) << 16);
}

// ---------------- degree ----------------
__global__ void k_deg_zero(int* __restrict__ deg) {
    int i = blockIdx.x * 256 + threadIdx.x;
    if (i < NN) deg[i] = 0;
}

__global__ void k_deg_count(const int* __restrict__ dstp, int* __restrict__ deg) {
    int e = blockIdx.x * 256 + threadIdx.x;
    if (e < EE) atomicAdd(&deg[dstp[e]], 1);
}

// ---------------- scan (exclusive prefix over deg) ----------------
__global__ __launch_bounds__(256) void k_scan1(const int* __restrict__ deg,
                                               int* __restrict__ partials) {
    int i = blockIdx.x * 256 + threadIdx.x;
    int v = (i < NN) ? deg[i] : 0;
    for (int o = 32; o; o >>= 1) v += __shfl_down(v, o, 64);
    __shared__ int sm[4];
    if ((threadIdx.x & 63) == 0) sm[threadIdx.x >> 6] = v;
    __syncthreads();
    if (threadIdx.x == 0) partials[blockIdx.x] = sm[0] + sm[1] + sm[2] + sm[3];
}

__global__ __launch_bounds__(512) void k_scan2(int* __restrict__ partials) {
    __shared__ int sm[512];
    int t = threadIdx.x;
    int v = (t < NCHUNK) ? partials[t] : 0;
    sm[t] = v;
    __syncthreads();
    for (int o = 1; o < 512; o <<= 1) {
        int add = (t >= o) ? sm[t - o] : 0;
        __syncthreads();
        sm[t] += add;
        __syncthreads();
    }
    if (t < NCHUNK) partials[t] = sm[t] - v;  // exclusive
}

__global__ __launch_bounds__(256) void k_scan3(const int* __restrict__ deg,
                                               const int* __restrict__ partials,
                                               int* __restrict__ row_off,
                                               int* __restrict__ cursor,
                                               float* __restrict__ dinv) {
    int t = threadIdx.x;
    int i = blockIdx.x * 256 + t;
    int v = (i < NN) ? deg[i] : 0;
    __shared__ int sm[256];
    sm[t] = v;
    __syncthreads();
    for (int o = 1; o < 256; o <<= 1) {
        int add = (t >= o) ? sm[t - o] : 0;
        __syncthreads();
        sm[t] += add;
        __syncthreads();
    }
    if (i < NN) {
        int excl = partials[blockIdx.x] + sm[t] - v;
        row_off[i] = excl;
        cursor[i] = excl;
        dinv[i] = rsqrtf((float)(v + 1));  // +1 self-loop
    }
}

// ---------------- CSR fill ----------------
__global__ void k_fill(const int* __restrict__ srcp, const int* __restrict__ dstp,
                       int* __restrict__ cursor, int* __restrict__ esrc) {
    int e = blockIdx.x * 256 + threadIdx.x;
    if (e < EE) {
        int d = dstp[e];
        int pos = atomicAdd(&cursor[d], 1);
        esrc[pos] = srcp[e];
    }
}

// ---------------- weight prep: transpose + bf16 ----------------
__global__ void k_prep(const float* __restrict__ W1,
                       const float* __restrict__ Wmu, const float* __restrict__ bmu,
                       const float* __restrict__ Wls, const float* __restrict__ bls,
                       short* __restrict__ wt, short* __restrict__ wct,
                       float* __restrict__ bcat) {
    int i = blockIdx.x * 256 + threadIdx.x;
    if (i < 32768) {
        int n = i >> 8, k = i & 255;
        wt[i] = f2bf(W1[k * HIDC + n]);
    } else if (i < 32768 + 16384) {
        int j = i - 32768;
        int n = j >> 7, k = j & 127;
        float v = (n < OUTC) ? Wmu[k * OUTC + n] : Wls[k * OUTC + (n - OUTC)];
        wct[j] = f2bf(v);
    } else if (i < 32768 + 16384 + 128) {
        int c = i - (32768 + 16384);
        bcat[c] = (c < OUTC) ? bmu[c] : bls[c - OUTC];
    }
}

// ---------------- MFMA GEMM1: out_bf16[M,128] = bf16(x[M,256]) @ wt^T ----------------
// 4 waves/block, each wave does M=32 (two 16-row tiles sharing B-frags).
__global__ __launch_bounds__(256) void k_mgemm1(const float* __restrict__ x,
                                                const short* __restrict__ wt,
                                                short* __restrict__ out) {
    int wave = threadIdx.x >> 6;
    int lane = threadIdx.x & 63;
    int m = lane & 15, quad = lane >> 4;
    int rbase = blockIdx.x * 128 + wave * 32;
    int r0c = min(rbase + m, NN - 1);
    int r1c = min(rbase + 16 + m, NN - 1);
    const float* xr0 = x + (size_t)r0c * INCH + quad * 8;
    const float* xr1 = x + (size_t)r1c * INCH + quad * 8;
    floatx4 acc0[8], acc1[8];
#pragma unroll
    for (int i = 0; i < 8; i++) { acc0[i] = (floatx4)(0.f); acc1[i] = (floatx4)(0.f); }
#pragma unroll
    for (int k0 = 0; k0 < INCH; k0 += 32) {
        float4 p00 = *(const float4*)(xr0 + k0);
        float4 p01 = *(const float4*)(xr0 + k0 + 4);
        float4 p10 = *(const float4*)(xr1 + k0);
        float4 p11 = *(const float4*)(xr1 + k0 + 4);
        short8 a0, a1;
        a0[0] = f2bf(p00.x); a0[1] = f2bf(p00.y); a0[2] = f2bf(p00.z); a0[3] = f2bf(p00.w);
        a0[4] = f2bf(p01.x); a0[5] = f2bf(p01.y); a0[6] = f2bf(p01.z); a0[7] = f2bf(p01.w);
        a1[0] = f2bf(p10.x); a1[1] = f2bf(p10.y); a1[2] = f2bf(p10.z); a1[3] = f2bf(p10.w);
        a1[4] = f2bf(p11.x); a1[5] = f2bf(p11.y); a1[6] = f2bf(p11.z); a1[7] = f2bf(p11.w);
        const short* wq = wt + k0 + quad * 8 + (size_t)m * INCH;
#pragma unroll
        for (int nt = 0; nt < 8; nt++) {
            short8 b = *(const short8*)(wq + (size_t)nt * 16 * INCH);
            acc0[nt] = __builtin_amdgcn_mfma_f32_16x16x32_bf16(a0, b, acc0[nt], 0, 0, 0);
            acc1[nt] = __builtin_amdgcn_mfma_f32_16x16x32_bf16(a1, b, acc1[nt], 0, 0, 0);
        }
    }
    int rs0 = rbase + quad * 4;
    int rs1 = rbase + 16 + quad * 4;
#pragma unroll
    for (int nt = 0; nt < 8; nt++) {
        int c = nt * 16 + m;
#pragma unroll
        for (int r = 0; r < 4; r++) {
            int rr = rs0 + r;
            if (rr < NN) out[(size_t)rr * HIDC + c] = f2bf(acc0[nt][r]);
            int rr2 = rs1 + r;
            if (rr2 < NN) out[(size_t)rr2 * HIDC + c] = f2bf(acc1[nt][r]);
        }
    }
}

// ---------------- MFMA GEMM2: [mu|logstd] = agg_bf16[M,128] @ wct^T + bcat ----------------
__global__ __launch_bounds__(256) void k_mgemm2(const short* __restrict__ agg,
                                                const short* __restrict__ wct,
                                                const float* __restrict__ bcat,
                                                float* __restrict__ out) {
    int wave = threadIdx.x >> 6;
    int lane = threadIdx.x & 63;
    int m = lane & 15, quad = lane >> 4;
    int rbase = blockIdx.x * 128 + wave * 32;
    int r0c = min(rbase + m, NN - 1);
    int r1c = min(rbase + 16 + m, NN - 1);
    const short* ar0 = agg + (size_t)r0c * HIDC + quad * 8;
    const short* ar1 = agg + (size_t)r1c * HIDC + quad * 8;
    floatx4 acc0[8], acc1[8];
#pragma unroll
    for (int i = 0; i < 8; i++) { acc0[i] = (floatx4)(0.f); acc1[i] = (floatx4)(0.f); }
#pragma unroll
    for (int k0 = 0; k0 < HIDC; k0 += 32) {
        short8 a0 = *(const short8*)(ar0 + k0);
        short8 a1 = *(const short8*)(ar1 + k0);
        const short* wq = wct + k0 + quad * 8 + (size_t)m * HIDC;
#pragma unroll
        for (int nt = 0; nt < 8; nt++) {
            short8 b = *(const short8*)(wq + (size_t)nt * 16 * HIDC);
            acc0[nt] = __builtin_amdgcn_mfma_f32_16x16x32_bf16(a0, b, acc0[nt], 0, 0, 0);
            acc1[nt] = __builtin_amdgcn_mfma_f32_16x16x32_bf16(a1, b, acc1[nt], 0, 0, 0);
        }
    }
    int rs0 = rbase + quad * 4;
    int rs1 = rbase + 16 + quad * 4;
#pragma unroll
    for (int nt = 0; nt < 8; nt++) {
        int c = nt * 16 + m;
        float bv = bcat[c];
        float* obase = (c < OUTC) ? (out + c) : (out + (size_t)NN * OUTC + (c - OUTC));
#pragma unroll
        for (int r = 0; r < 4; r++) {
            int rr = rs0 + r;
            if (rr < NN) obase[(size_t)rr * OUTC] = acc0[nt][r] + bv;
            int rr2 = rs1 + r;
            if (rr2 < NN) obase[(size_t)rr2 * OUTC] = acc1[nt][r] + bv;
        }
    }
}

// ---------------- gather aggregation: 16 lanes per dst row, bf16 in/out ----------------
template <bool RELU>
__global__ __launch_bounds__(256) void k_gather(const short* __restrict__ feat,
                                                const int* __restrict__ esrc,
                                                const int* __restrict__ row_off,
                                                const int* __restrict__ deg,
                                                const float* __restrict__ dinv,
                                                const float* __restrict__ bias,
                                                short* __restrict__ out) {
    int gid = blockIdx.x * 256 + threadIdx.x;
    int d = gid >> 4;          // one 16-lane group per dst node
    int l = threadIdx.x & 15;  // 16 lanes x 8 ch (ushort8) = 128 ch
    if (d >= NN) return;
    const ushort8* fp = (const ushort8*)feat;
    float dd = dinv[d];
    float sw = dd * dd;
    ushort8 sv = fp[(size_t)d * 16 + l];
    float acc[8];
#pragma unroll
    for (int i = 0; i < 8; i++) acc[i] = bf2f(sv[i]) * sw;
    int off = row_off[d];
    int cnt = deg[d];
    for (int base = 0; base < cnt; base += 16) {
        int mm = min(16, cnt - base);
        int sj = (l < mm) ? esrc[off + base + l] : 0;
        float dj = (l < mm) ? dinv[sj] : 0.f;
        for (int j = 0; j < mm; j++) {
            int s = __shfl(sj, j, 16);
            float nw = __shfl(dj, j, 16) * dd;
            ushort8 v = fp[(size_t)s * 16 + l];
#pragma unroll
            for (int i = 0; i < 8; i++) acc[i] = fmaf(bf2f(v[i]), nw, acc[i]);
        }
    }
    if (RELU) {
        float4 b0 = *(const float4*)(bias + l * 8);
        float4 b1 = *(const float4*)(bias + l * 8 + 4);
        acc[0] = fmaxf(acc[0] + b0.x, 0.f);
        acc[1] = fmaxf(acc[1] + b0.y, 0.f);
        acc[2] = fmaxf(acc[2] + b0.z, 0.f);
        acc[3] = fmaxf(acc[3] + b0.w, 0.f);
        acc[4] = fmaxf(acc[4] + b1.x, 0.f);
        acc[5] = fmaxf(acc[5] + b1.y, 0.f);
        acc[6] = fmaxf(acc[6] + b1.z, 0.f);
        acc[7] = fmaxf(acc[7] + b1.w, 0.f);
    }
    ushort8 o;
#pragma unroll
    for (int i = 0; i < 8; i++) o[i] = (unsigned short)f2bf(acc[i]);
    ((ushort8*)out)[(size_t)d * 16 + l] = o;
}

extern "C" void kernel_launch(void* const* d_in, const int* in_sizes, int n_in,
                              void* d_out, int out_size, void* d_ws, size_t ws_size,
                              hipStream_t stream) {
    const float* x   = (const float*)d_in[0];
    const float* W1  = (const float*)d_in[1];
    const float* b1  = (const float*)d_in[2];
    const float* Wmu = (const float*)d_in[3];
    const float* bmu = (const float*)d_in[4];
    const float* Wls = (const float*)d_in[5];
    const float* bls = (const float*)d_in[6];
    const int*   ei  = (const int*)d_in[7];
    const int* srcp = ei;        // edge_index[0]
    const int* dstp = ei + EE;   // edge_index[1]

    float* out = (float*)d_out;

    // workspace layout
    char* wsb = (char*)d_ws;
    short* bufA    = (short*)wsb;                        // N*128 bf16: XW1, then agg2 (25.6 MB)
    short* bufH    = bufA + (size_t)NN * HIDC;           // N*128 bf16: h (25.6 MB)
    int*   deg     = (int*)(bufH + (size_t)NN * HIDC);
    int*   row_off = deg + NN;
    int*   cursor  = row_off + NN;
    float* dinv    = (float*)(cursor + NN);
    int*   esrc    = (int*)(dinv + NN);                  // E ints
    int*   partials = esrc + EE;                         // NCHUNK ints
    short* wt      = (short*)(partials + NCHUNK + 1);    // 128*256 bf16
    short* wct     = wt + 128 * 256;                     // 128*128 bf16
    float* bcat    = (float*)(wct + 128 * 128);          // 128 f32

    const int nb_n = (NN + 255) / 256;
    const int nb_e = (EE + 255) / 256;
    const int nb_g = (NN * 16) / 256;          // 6250 exact
    const int nb_m = (NN + 127) / 128;         // 782 MFMA blocks

    // CSR build + norm + weight prep
    k_deg_zero<<<nb_n, 256, 0, stream>>>(deg);
    k_deg_count<<<nb_e, 256, 0, stream>>>(dstp, deg);
    k_scan1<<<NCHUNK, 256, 0, stream>>>(deg, partials);
    k_scan2<<<1, 512, 0, stream>>>(partials);
    k_scan3<<<NCHUNK, 256, 0, stream>>>(deg, partials, row_off, cursor, dinv);
    k_fill<<<nb_e, 256, 0, stream>>>(srcp, dstp, cursor, esrc);
    k_prep<<<193, 256, 0, stream>>>(W1, Wmu, bmu, Wls, bls, wt, wct, bcat);

    // layer 1: XW1 -> bufA (bf16, MFMA); h = relu(agg(bufA) + b1) -> bufH (bf16)
    k_mgemm1<<<nb_m, 256, 0, stream>>>(x, wt, bufA);
    k_gather<true><<<nb_g, 256, 0, stream>>>(bufA, esrc, row_off, deg, dinv, b1, bufH);

    // layer 2/3: agg2 = agg(h) -> bufA (bf16); [mu|logstd] = bufA @ wct^T + bcat -> d_out
    k_gather<false><<<nb_g, 256, 0, stream>>>(bufH, esrc, row_off, deg, dinv, nullptr, bufA);
    k_mgemm2<<<nb_m, 256, 0, stream>>>(bufA, wct, bcat, out);
}

// Round 6
// 379.013 us; speedup vs baseline: 8.0804x; 1.0111x over previous
//
#include <hip/hip_runtime.h>
#include <math.h>

#define NN 100000
#define EE 640000
#define INCH 256
#define HIDC 128
#define OUTC 64
#define NCHUNK ((NN + 255) / 256)   // 391 scan chunks

typedef __attribute__((ext_vector_type(8))) short short8;
typedef __attribute__((ext_vector_type(8))) unsigned short ushort8;
typedef __attribute__((ext_vector_type(4))) float floatx4;

__device__ __forceinline__ short f2bf(float f) {
    unsigned u = __float_as_uint(f);
    u += 0x7fff + ((u >> 16) & 1);   // round-to-nearest-even
    return (short)(u >> 16);
}

__device__ __forceinline__ float bf2f(unsigned short u) {
    return __uint_as_float(((unsigned)u) << 16);
}

// ---------------- degree ----------------
__global__ void k_deg_zero(int* __restrict__ deg) {
    int i = blockIdx.x * 256 + threadIdx.x;
    if (i < NN) deg[i] = 0;
}

__global__ void k_deg_count(const int* __restrict__ dstp, int* __restrict__ deg) {
    int e = blockIdx.x * 256 + threadIdx.x;
    if (e < EE) atomicAdd(&deg[dstp[e]], 1);
}

// ---------------- scan (exclusive prefix over deg) ----------------
__global__ __launch_bounds__(256) void k_scan1(const int* __restrict__ deg,
                                               int* __restrict__ partials) {
    int i = blockIdx.x * 256 + threadIdx.x;
    int v = (i < NN) ? deg[i] : 0;
    for (int o = 32; o; o >>= 1) v += __shfl_down(v, o, 64);
    __shared__ int sm[4];
    if ((threadIdx.x & 63) == 0) sm[threadIdx.x >> 6] = v;
    __syncthreads();
    if (threadIdx.x == 0) partials[blockIdx.x] = sm[0] + sm[1] + sm[2] + sm[3];
}

__global__ __launch_bounds__(512) void k_scan2(int* __restrict__ partials) {
    __shared__ int sm[512];
    int t = threadIdx.x;
    int v = (t < NCHUNK) ? partials[t] : 0;
    sm[t] = v;
    __syncthreads();
    for (int o = 1; o < 512; o <<= 1) {
        int add = (t >= o) ? sm[t - o] : 0;
        __syncthreads();
        sm[t] += add;
        __syncthreads();
    }
    if (t < NCHUNK) partials[t] = sm[t] - v;  // exclusive
}

__global__ __launch_bounds__(256) void k_scan3(const int* __restrict__ deg,
                                               const int* __restrict__ partials,
                                               int* __restrict__ row_off,
                                               int* __restrict__ cursor,
                                               float* __restrict__ dinv) {
    int t = threadIdx.x;
    int i = blockIdx.x * 256 + t;
    int v = (i < NN) ? deg[i] : 0;
    __shared__ int sm[256];
    sm[t] = v;
    __syncthreads();
    for (int o = 1; o < 256; o <<= 1) {
        int add = (t >= o) ? sm[t - o] : 0;
        __syncthreads();
        sm[t] += add;
        __syncthreads();
    }
    if (i < NN) {
        int excl = partials[blockIdx.x] + sm[t] - v;
        row_off[i] = excl;
        cursor[i] = excl;
        dinv[i] = rsqrtf((float)(v + 1));  // +1 self-loop
    }
}

// ---------------- CSR fill ----------------
__global__ void k_fill(const int* __restrict__ srcp, const int* __restrict__ dstp,
                       int* __restrict__ cursor, int* __restrict__ esrc) {
    int e = blockIdx.x * 256 + threadIdx.x;
    if (e < EE) {
        int d = dstp[e];
        int pos = atomicAdd(&cursor[d], 1);
        esrc[pos] = srcp[e];
    }
}

// ---------------- weight prep: transpose + bf16 ----------------
__global__ void k_prep(const float* __restrict__ W1,
                       const float* __restrict__ Wmu, const float* __restrict__ bmu,
                       const float* __restrict__ Wls, const float* __restrict__ bls,
                       short* __restrict__ wt, short* __restrict__ wct,
                       float* __restrict__ bcat) {
    int i = blockIdx.x * 256 + threadIdx.x;
    if (i < 32768) {
        int n = i >> 8, k = i & 255;
        wt[i] = f2bf(W1[k * HIDC + n]);
    } else if (i < 32768 + 16384) {
        int j = i - 32768;
        int n = j >> 7, k = j & 127;
        float v = (n < OUTC) ? Wmu[k * OUTC + n] : Wls[k * OUTC + (n - OUTC)];
        wct[j] = f2bf(v);
    } else if (i < 32768 + 16384 + 128) {
        int c = i - (32768 + 16384);
        bcat[c] = (c < OUTC) ? bmu[c] : bls[c - OUTC];
    }
}

// ---------------- MFMA GEMM1: out_bf16[M,128] = bf16(x[M,256]) @ wt^T ----------------
// block = 64 rows; wave (rhalf, chalf): M=32 (2 A-tiles) x N=64 (4 B-tiles).
__global__ __launch_bounds__(256) void k_mgemm1(const float* __restrict__ x,
                                                const short* __restrict__ wt,
                                                short* __restrict__ out) {
    int wave = threadIdx.x >> 6;
    int lane = threadIdx.x & 63;
    int rhalf = wave & 1, chalf = wave >> 1;
    int m = lane & 15, quad = lane >> 4;
    int rbase = blockIdx.x * 64 + rhalf * 32;
    int r0c = min(rbase + m, NN - 1);
    int r1c = min(rbase + 16 + m, NN - 1);
    const float* xr0 = x + (size_t)r0c * INCH + quad * 8;
    const float* xr1 = x + (size_t)r1c * INCH + quad * 8;
    const short* wbase = wt + quad * 8 + (size_t)m * INCH + (size_t)(chalf * 4) * 16 * INCH;
    floatx4 acc0[4], acc1[4];
#pragma unroll
    for (int i = 0; i < 4; i++) { acc0[i] = (floatx4)(0.f); acc1[i] = (floatx4)(0.f); }
#pragma unroll
    for (int k0 = 0; k0 < INCH; k0 += 32) {
        float4 p00 = *(const float4*)(xr0 + k0);
        float4 p01 = *(const float4*)(xr0 + k0 + 4);
        float4 p10 = *(const float4*)(xr1 + k0);
        float4 p11 = *(const float4*)(xr1 + k0 + 4);
        short8 a0, a1;
        a0[0] = f2bf(p00.x); a0[1] = f2bf(p00.y); a0[2] = f2bf(p00.z); a0[3] = f2bf(p00.w);
        a0[4] = f2bf(p01.x); a0[5] = f2bf(p01.y); a0[6] = f2bf(p01.z); a0[7] = f2bf(p01.w);
        a1[0] = f2bf(p10.x); a1[1] = f2bf(p10.y); a1[2] = f2bf(p10.z); a1[3] = f2bf(p10.w);
        a1[4] = f2bf(p11.x); a1[5] = f2bf(p11.y); a1[6] = f2bf(p11.z); a1[7] = f2bf(p11.w);
        const short* wq = wbase + k0;
#pragma unroll
        for (int nt = 0; nt < 4; nt++) {
            short8 b = *(const short8*)(wq + (size_t)nt * 16 * INCH);
            acc0[nt] = __builtin_amdgcn_mfma_f32_16x16x32_bf16(a0, b, acc0[nt], 0, 0, 0);
            acc1[nt] = __builtin_amdgcn_mfma_f32_16x16x32_bf16(a1, b, acc1[nt], 0, 0, 0);
        }
    }
    int rs0 = rbase + quad * 4;
    int rs1 = rbase + 16 + quad * 4;
#pragma unroll
    for (int nt = 0; nt < 4; nt++) {
        int c = (chalf * 4 + nt) * 16 + m;
#pragma unroll
        for (int r = 0; r < 4; r++) {
            int rr = rs0 + r;
            if (rr < NN) out[(size_t)rr * HIDC + c] = f2bf(acc0[nt][r]);
            int rr2 = rs1 + r;
            if (rr2 < NN) out[(size_t)rr2 * HIDC + c] = f2bf(acc1[nt][r]);
        }
    }
}

// ---------------- MFMA GEMM2: [mu|logstd] = agg_bf16[M,128] @ wct^T + bcat ----------------
__global__ __launch_bounds__(256) void k_mgemm2(const short* __restrict__ agg,
                                                const short* __restrict__ wct,
                                                const float* __restrict__ bcat,
                                                float* __restrict__ out) {
    int wave = threadIdx.x >> 6;
    int lane = threadIdx.x & 63;
    int rhalf = wave & 1, chalf = wave >> 1;
    int m = lane & 15, quad = lane >> 4;
    int rbase = blockIdx.x * 64 + rhalf * 32;
    int r0c = min(rbase + m, NN - 1);
    int r1c = min(rbase + 16 + m, NN - 1);
    const short* ar0 = agg + (size_t)r0c * HIDC + quad * 8;
    const short* ar1 = agg + (size_t)r1c * HIDC + quad * 8;
    const short* wbase = wct + quad * 8 + (size_t)m * HIDC + (size_t)(chalf * 4) * 16 * HIDC;
    floatx4 acc0[4], acc1[4];
#pragma unroll
    for (int i = 0; i < 4; i++) { acc0[i] = (floatx4)(0.f); acc1[i] = (floatx4)(0.f); }
#pragma unroll
    for (int k0 = 0; k0 < HIDC; k0 += 32) {
        short8 a0 = *(const short8*)(ar0 + k0);
        short8 a1 = *(const short8*)(ar1 + k0);
        const short* wq = wbase + k0;
#pragma unroll
        for (int nt = 0; nt < 4; nt++) {
            short8 b = *(const short8*)(wq + (size_t)nt * 16 * HIDC);
            acc0[nt] = __builtin_amdgcn_mfma_f32_16x16x32_bf16(a0, b, acc0[nt], 0, 0, 0);
            acc1[nt] = __builtin_amdgcn_mfma_f32_16x16x32_bf16(a1, b, acc1[nt], 0, 0, 0);
        }
    }
    int rs0 = rbase + quad * 4;
    int rs1 = rbase + 16 + quad * 4;
#pragma unroll
    for (int nt = 0; nt < 4; nt++) {
        int c = (chalf * 4 + nt) * 16 + m;
        float bv = bcat[c];
        float* obase = (c < OUTC) ? (out + c) : (out + (size_t)NN * OUTC + (c - OUTC));
#pragma unroll
        for (int r = 0; r < 4; r++) {
            int rr = rs0 + r;
            if (rr < NN) obase[(size_t)rr * OUTC] = acc0[nt][r] + bv;
            int rr2 = rs1 + r;
            if (rr2 < NN) obase[(size_t)rr2 * OUTC] = acc1[nt][r] + bv;
        }
    }
}

// ---------------- gather aggregation: 16 lanes per dst row, bf16 in/out, 4x unrolled ----------------
template <bool RELU>
__global__ __launch_bounds__(256) void k_gather(const short* __restrict__ feat,
                                                const int* __restrict__ esrc,
                                                const int* __restrict__ row_off,
                                                const int* __restrict__ deg,
                                                const float* __restrict__ dinv,
                                                const float* __restrict__ bias,
                                                short* __restrict__ out) {
    int gid = blockIdx.x * 256 + threadIdx.x;
    int d = gid >> 4;          // one 16-lane group per dst node
    int l = threadIdx.x & 15;  // 16 lanes x 8 ch (ushort8) = 128 ch
    if (d >= NN) return;
    const ushort8* fp = (const ushort8*)feat;
    float dd = dinv[d];
    float sw = dd * dd;
    ushort8 sv = fp[(size_t)d * 16 + l];
    float acc[8];
#pragma unroll
    for (int i = 0; i < 8; i++) acc[i] = bf2f(sv[i]) * sw;
    int off = row_off[d];
    int cnt = deg[d];
    for (int base = 0; base < cnt; base += 16) {
        int mm = min(16, cnt - base);
        int sj = (l < mm) ? esrc[off + base + l] : 0;
        float dj = (l < mm) ? dinv[sj] : 0.f;
        int j = 0;
        for (; j + 4 <= mm; j += 4) {
            int s0 = __shfl(sj, j + 0, 16);
            int s1 = __shfl(sj, j + 1, 16);
            int s2 = __shfl(sj, j + 2, 16);
            int s3 = __shfl(sj, j + 3, 16);
            float n0 = __shfl(dj, j + 0, 16) * dd;
            float n1 = __shfl(dj, j + 1, 16) * dd;
            float n2 = __shfl(dj, j + 2, 16) * dd;
            float n3 = __shfl(dj, j + 3, 16) * dd;
            ushort8 v0 = fp[(size_t)s0 * 16 + l];
            ushort8 v1 = fp[(size_t)s1 * 16 + l];
            ushort8 v2 = fp[(size_t)s2 * 16 + l];
            ushort8 v3 = fp[(size_t)s3 * 16 + l];
#pragma unroll
            for (int i = 0; i < 8; i++) acc[i] = fmaf(bf2f(v0[i]), n0, acc[i]);
#pragma unroll
            for (int i = 0; i < 8; i++) acc[i] = fmaf(bf2f(v1[i]), n1, acc[i]);
#pragma unroll
            for (int i = 0; i < 8; i++) acc[i] = fmaf(bf2f(v2[i]), n2, acc[i]);
#pragma unroll
            for (int i = 0; i < 8; i++) acc[i] = fmaf(bf2f(v3[i]), n3, acc[i]);
        }
        if (j + 2 <= mm) {
            int s0 = __shfl(sj, j + 0, 16);
            int s1 = __shfl(sj, j + 1, 16);
            float n0 = __shfl(dj, j + 0, 16) * dd;
            float n1 = __shfl(dj, j + 1, 16) * dd;
            ushort8 v0 = fp[(size_t)s0 * 16 + l];
            ushort8 v1 = fp[(size_t)s1 * 16 + l];
#pragma unroll
            for (int i = 0; i < 8; i++) acc[i] = fmaf(bf2f(v0[i]), n0, acc[i]);
#pragma unroll
            for (int i = 0; i < 8; i++) acc[i] = fmaf(bf2f(v1[i]), n1, acc[i]);
            j += 2;
        }
        if (j < mm) {
            int s0 = __shfl(sj, j, 16);
            float n0 = __shfl(dj, j, 16) * dd;
            ushort8 v0 = fp[(size_t)s0 * 16 + l];
#pragma unroll
            for (int i = 0; i < 8; i++) acc[i] = fmaf(bf2f(v0[i]), n0, acc[i]);
        }
    }
    if (RELU) {
        float4 b0 = *(const float4*)(bias + l * 8);
        float4 b1 = *(const float4*)(bias + l * 8 + 4);
        acc[0] = fmaxf(acc[0] + b0.x, 0.f);
        acc[1] = fmaxf(acc[1] + b0.y, 0.f);
        acc[2] = fmaxf(acc[2] + b0.z, 0.f);
        acc[3] = fmaxf(acc[3] + b0.w, 0.f);
        acc[4] = fmaxf(acc[4] + b1.x, 0.f);
        acc[5] = fmaxf(acc[5] + b1.y, 0.f);
        acc[6] = fmaxf(acc[6] + b1.z, 0.f);
        acc[7] = fmaxf(acc[7] + b1.w, 0.f);
    }
    ushort8 o;
#pragma unroll
    for (int i = 0; i < 8; i++) o[i] = (unsigned short)f2bf(acc[i]);
    ((ushort8*)out)[(size_t)d * 16 + l] = o;
}

extern "C" void kernel_launch(void* const* d_in, const int* in_sizes, int n_in,
                              void* d_out, int out_size, void* d_ws, size_t ws_size,
                              hipStream_t stream) {
    const float* x   = (const float*)d_in[0];
    const float* W1  = (const float*)d_in[1];
    const float* b1  = (const float*)d_in[2];
    const float* Wmu = (const float*)d_in[3];
    const float* bmu = (const float*)d_in[4];
    const float* Wls = (const float*)d_in[5];
    const float* bls = (const float*)d_in[6];
    const int*   ei  = (const int*)d_in[7];
    const int* srcp = ei;        // edge_index[0]
    const int* dstp = ei + EE;   // edge_index[1]

    float* out = (float*)d_out;

    // workspace layout
    char* wsb = (char*)d_ws;
    short* bufA    = (short*)wsb;                        // N*128 bf16: XW1, then agg2 (25.6 MB)
    short* bufH    = bufA + (size_t)NN * HIDC;           // N*128 bf16: h (25.6 MB)
    int*   deg     = (int*)(bufH + (size_t)NN * HIDC);
    int*   row_off = deg + NN;
    int*   cursor  = row_off + NN;
    float* dinv    = (float*)(cursor + NN);
    int*   esrc    = (int*)(dinv + NN);                  // E ints
    int*   partials = esrc + EE;                         // NCHUNK ints
    short* wt      = (short*)(partials + NCHUNK + 1);    // 128*256 bf16
    short* wct     = wt + 128 * 256;                     // 128*128 bf16
    float* bcat    = (float*)(wct + 128 * 128);          // 128 f32

    const int nb_n = (NN + 255) / 256;
    const int nb_e = (EE + 255) / 256;
    const int nb_g = (NN * 16) / 256;          // 6250 exact
    const int nb_m = (NN + 63) / 64;           // 1563 MFMA blocks

    // CSR build + norm + weight prep
    k_deg_zero<<<nb_n, 256, 0, stream>>>(deg);
    k_deg_count<<<nb_e, 256, 0, stream>>>(dstp, deg);
    k_scan1<<<NCHUNK, 256, 0, stream>>>(deg, partials);
    k_scan2<<<1, 512, 0, stream>>>(partials);
    k_scan3<<<NCHUNK, 256, 0, stream>>>(deg, partials, row_off, cursor, dinv);
    k_fill<<<nb_e, 256, 0, stream>>>(srcp, dstp, cursor, esrc);
    k_prep<<<193, 256, 0, stream>>>(W1, Wmu, bmu, Wls, bls, wt, wct, bcat);

    // layer 1: XW1 -> bufA (bf16, MFMA); h = relu(agg(bufA) + b1) -> bufH (bf16)
    k_mgemm1<<<nb_m, 256, 0, stream>>>(x, wt, bufA);
    k_gather<true><<<nb_g, 256, 0, stream>>>(bufA, esrc, row_off, deg, dinv, b1, bufH);

    // layer 2/3: agg2 = agg(h) -> bufA (bf16); [mu|logstd] = bufA @ wct^T + bcat -> d_out
    k_gather<false><<<nb_g, 256, 0, stream>>>(bufH, esrc, row_off, deg, dinv, nullptr, bufA);
    k_mgemm2<<<nb_m, 256, 0, stream>>>(bufA, wct, bcat, out);
}